// Round 2
// baseline (279.408 us; speedup 1.0000x reference)
//
#include <hip/hip_runtime.h>
#include <math.h>

#define NB 32
#define NB2 1024
#define EPS 1e-5f

// Joint histogram: per-block LDS histogram + global atomic flush.
// 2048 blocks x 256 thr = 8 blocks/CU, 32 waves/CU (100% occupancy).
// Unroll x4: 8 independent float4 loads in flight before any dependent use.
__global__ __launch_bounds__(256, 8) void hist_kernel(const float4* __restrict__ I4,
                                                      const float4* __restrict__ J4,
                                                      unsigned int* __restrict__ hist,
                                                      int n4) {
    __shared__ unsigned int lh[NB2];
    const int t = threadIdx.x;
    for (int i = t; i < NB2; i += 256) lh[i] = 0u;
    __syncthreads();

    const float s = 31.0f / 255.0f;  // bit-exact vs /255*31+round (verified R0: absmax 0)
    const int stride = gridDim.x * 1024;
    int i = blockIdx.x * 1024 + t;

    for (; i + 768 < n4; i += stride) {
        // issue all 8 loads up front (independent -> overlapped vmcnt)
        float4 a0 = I4[i];
        float4 a1 = I4[i + 256];
        float4 a2 = I4[i + 512];
        float4 a3 = I4[i + 768];
        float4 b0 = J4[i];
        float4 b1 = J4[i + 256];
        float4 b2 = J4[i + 512];
        float4 b3 = J4[i + 768];
        atomicAdd(&lh[((int)rintf(a0.x * s) << 5) | (int)rintf(b0.x * s)], 1u);
        atomicAdd(&lh[((int)rintf(a0.y * s) << 5) | (int)rintf(b0.y * s)], 1u);
        atomicAdd(&lh[((int)rintf(a0.z * s) << 5) | (int)rintf(b0.z * s)], 1u);
        atomicAdd(&lh[((int)rintf(a0.w * s) << 5) | (int)rintf(b0.w * s)], 1u);
        atomicAdd(&lh[((int)rintf(a1.x * s) << 5) | (int)rintf(b1.x * s)], 1u);
        atomicAdd(&lh[((int)rintf(a1.y * s) << 5) | (int)rintf(b1.y * s)], 1u);
        atomicAdd(&lh[((int)rintf(a1.z * s) << 5) | (int)rintf(b1.z * s)], 1u);
        atomicAdd(&lh[((int)rintf(a1.w * s) << 5) | (int)rintf(b1.w * s)], 1u);
        atomicAdd(&lh[((int)rintf(a2.x * s) << 5) | (int)rintf(b2.x * s)], 1u);
        atomicAdd(&lh[((int)rintf(a2.y * s) << 5) | (int)rintf(b2.y * s)], 1u);
        atomicAdd(&lh[((int)rintf(a2.z * s) << 5) | (int)rintf(b2.z * s)], 1u);
        atomicAdd(&lh[((int)rintf(a2.w * s) << 5) | (int)rintf(b2.w * s)], 1u);
        atomicAdd(&lh[((int)rintf(a3.x * s) << 5) | (int)rintf(b3.x * s)], 1u);
        atomicAdd(&lh[((int)rintf(a3.y * s) << 5) | (int)rintf(b3.y * s)], 1u);
        atomicAdd(&lh[((int)rintf(a3.z * s) << 5) | (int)rintf(b3.z * s)], 1u);
        atomicAdd(&lh[((int)rintf(a3.w * s) << 5) | (int)rintf(b3.w * s)], 1u);
    }
    // remainder (not taken for n4 = 2^23 with this grid, but stay general)
    for (int k = 0; k < 4; ++k) {
        int idx = i + k * 256;
        if (idx < n4) {
            float4 a = I4[idx];
            float4 b = J4[idx];
            atomicAdd(&lh[((int)rintf(a.x * s) << 5) | (int)rintf(b.x * s)], 1u);
            atomicAdd(&lh[((int)rintf(a.y * s) << 5) | (int)rintf(b.y * s)], 1u);
            atomicAdd(&lh[((int)rintf(a.z * s) << 5) | (int)rintf(b.z * s)], 1u);
            atomicAdd(&lh[((int)rintf(a.w * s) << 5) | (int)rintf(b.w * s)], 1u);
        }
    }
    __syncthreads();

    for (int k = t; k < NB2; k += 256) {
        unsigned int c = lh[k];
        if (c) atomicAdd(&hist[k], c);
    }
}

// probs -> marginals -> MI -> sigmoid(-mi). One block, 1024 threads.
__global__ __launch_bounds__(1024) void mi_kernel(const unsigned int* __restrict__ hist,
                                                  float* __restrict__ out,
                                                  float invN) {
    __shared__ float jp[NB2];
    __shared__ float Ip[NB];
    __shared__ float Jp[NB];
    __shared__ float wsum[16];

    const int t = threadIdx.x;
    float p = (float)hist[t] * invN;  // invN = 2^-25: exact
    jp[t] = p;
    __syncthreads();

    if (t < NB) {  // row sums (marginal over J)
        float acc = 0.0f;
        for (int c = 0; c < NB; ++c) acc += jp[(t << 5) | c];
        Ip[t] = acc;
    } else if (t < 2 * NB) {  // col sums (marginal over I)
        int c = t - NB;
        float acc = 0.0f;
        for (int r = 0; r < NB; ++r) acc += jp[(r << 5) | c];
        Jp[c] = acc;
    }
    __syncthreads();

    float term = p * (logf(p + EPS) - logf(Ip[t >> 5] + EPS) - logf(Jp[t & 31] + EPS));

    for (int off = 32; off > 0; off >>= 1) term += __shfl_down(term, off, 64);
    const int wave = t >> 6;
    if ((t & 63) == 0) wsum[wave] = term;
    __syncthreads();

    if (t == 0) {
        float mi = 0.0f;
        for (int w = 0; w < 16; ++w) mi += wsum[w];
        out[0] = 1.0f / (1.0f + expf(mi));  // sigmoid(-mi)
    }
}

extern "C" void kernel_launch(void* const* d_in, const int* in_sizes, int n_in,
                              void* d_out, int out_size, void* d_ws, size_t ws_size,
                              hipStream_t stream) {
    const float4* I4 = (const float4*)d_in[0];
    const float4* J4 = (const float4*)d_in[1];
    unsigned int* hist = (unsigned int*)d_ws;  // 4 KiB of workspace
    const int n = in_sizes[0];                 // 33,554,432
    const int n4 = n >> 2;

    hipMemsetAsync(hist, 0, NB2 * sizeof(unsigned int), stream);
    hist_kernel<<<2048, 256, 0, stream>>>(I4, J4, hist, n4);
    mi_kernel<<<1, 1024, 0, stream>>>(hist, (float*)d_out, 1.0f / (float)n);
}